// Round 8
// baseline (4687.102 us; speedup 1.0000x reference)
//
#include <hip/hip_runtime.h>

#define WAVE 64
#define FPS_SPLIT 4

// ---------------------------------------------------------------------------
// split pointcloud (B,N,6) -> xyz (B,N,3) + feats (B,N,3)
__global__ __launch_bounds__(256) void split_kernel(const float* __restrict__ pc,
    float* __restrict__ xyz, float* __restrict__ feats, int total) {
  int t = blockIdx.x * blockDim.x + threadIdx.x;
  if (t >= total) return;
  const float* p = pc + (size_t)t * 6;
  xyz[t * 3 + 0] = p[0]; xyz[t * 3 + 1] = p[1]; xyz[t * 3 + 2] = p[2];
  feats[t * 3 + 0] = p[3]; feats[t * 3 + 1] = p[4]; feats[t * 3 + 2] = p[5];
}

__global__ __launch_bounds__(256) void zero_kernel(float* __restrict__ p, int n) {
  int t = blockIdx.x * blockDim.x + threadIdx.x;
  if (t < n) p[t] = 0.f;
}

// ---------------------------------------------------------------------------
// Wave-wide reductions via DPP (VALU pipe only — no ds_swizzle LDS traffic).
// rocPRIM pattern: row_shr 1/2/4/8 + row_bcast15/31; full max lands in lane 63.
__device__ __forceinline__ float dpp_max_f32(float v) {
#define DPP_STEP_F(ctrl) { int t_ = __builtin_amdgcn_update_dpp( \
      __float_as_int(v), __float_as_int(v), ctrl, 0xf, 0xf, false); \
    v = fmaxf(v, __int_as_float(t_)); }
  DPP_STEP_F(0x111) DPP_STEP_F(0x112) DPP_STEP_F(0x114)
  DPP_STEP_F(0x118) DPP_STEP_F(0x142) DPP_STEP_F(0x143)
#undef DPP_STEP_F
  return v;  // valid in lane 63
}
__device__ __forceinline__ unsigned dpp_max_u32(unsigned v) {
#define DPP_STEP_U(ctrl) { unsigned t_ = (unsigned)__builtin_amdgcn_update_dpp( \
      (int)v, (int)v, ctrl, 0xf, 0xf, false); \
    v = (t_ > v) ? t_ : v; }
  DPP_STEP_U(0x111) DPP_STEP_U(0x112) DPP_STEP_U(0x114)
  DPP_STEP_U(0x118) DPP_STEP_U(0x142) DPP_STEP_U(0x143)
#undef DPP_STEP_U
  return v;  // valid in lane 63
}
__device__ __forceinline__ unsigned bcast63(unsigned v) {
  return (unsigned)__builtin_amdgcn_readlane((int)v, 63);
}

// ---------------------------------------------------------------------------
// FPS, layer 0: N=16384, 4 blocks per batch x 1024 threads (4 points/thread).
// Round 5-7 post-mortem: three different single-block main loops all plateau
// at ~1700us, per-CU VALUBusy ~87-90% => truly VALU-issue-bound on 8 CUs.
// This version quarters the per-CU work and syncs the 4 blocks of a batch
// each iteration with device-scope atomics:
//   publish:  atomicMax(gkey[it%3], blockKey); __threadfence();
//   barrier:  atomicAdd(garr,1); spin until garr >= 4*it  (monotonic, no ABA)
//   consume:  atomicMax(gkey[it%3], 0) read-back; reset slot (it+2)%3
// Slot-reset safety: writers of slot it+2 must first pass the spin of it+1,
// which orders them after every block's reset at it. Max over disjoint
// partitions is exact; tie-break = global inverted-index max => bit-identical
// picks vs the single-block version. All 32 blocks are co-resident (256 CUs).
// Exact math: ((dx*dx+dy*dy)+dz*dz) with explicit _rn ops, no FMA.
__global__ __launch_bounds__(1024, 4) void fps_big_kernel(const float* __restrict__ xyz,
    float* __restrict__ new_xyz, unsigned long long* __restrict__ gsync, int N, int S) {
  const int blk = blockIdx.x;
  const int b = blk >> 2;
  const int sub = blk & 3;
  const int tid = threadIdx.x;
  const int lane = tid & 63;
  const float* px = xyz + (size_t)b * N * 3;
  unsigned long long* gkey = gsync + (size_t)b * 4;   // slots 0..2
  unsigned long long* garr = gkey + 3;                // arrive counter
  __shared__ unsigned long long s_key[3];
  __shared__ unsigned long long s_bkey;
  const int base = sub << 12;                         // sub * 4096
  float rx[4], ry[4], rz[4], mind[4];
#pragma unroll
  for (int p = 0; p < 4; ++p) {
    int i = base + tid + (p << 10);
    rx[p] = px[i * 3 + 0]; ry[p] = px[i * 3 + 1]; rz[p] = px[i * 3 + 2];
    asm volatile("" : "+v"(rx[p]), "+v"(ry[p]), "+v"(rz[p]));
    mind[p] = 1e10f;
  }
  if (tid < 3) s_key[tid] = 0ull;
  float qx = px[0], qy = px[1], qz = px[2];   // pick 0 is always index 0
  if (sub == 0 && tid == 0) {
    float* o = new_xyz + (size_t)b * S * 3;
    o[0] = qx; o[1] = qy; o[2] = qz;
  }
  __syncthreads();
  for (unsigned it = 1; it < (unsigned)S; ++it) {
    float bestv = -1.f; unsigned besti = 0;
#pragma unroll
    for (int p = 0; p < 4; ++p) {
      float dx = __fsub_rn(rx[p], qx);
      float dy = __fsub_rn(ry[p], qy);
      float dz = __fsub_rn(rz[p], qz);
      float d = __fadd_rn(__fadd_rn(__fmul_rn(dx, dx), __fmul_rn(dy, dy)), __fmul_rn(dz, dz));
      float mo = fminf(mind[p], d);
      mind[p] = mo;
      // p ascending => index ascending within thread: keeps first max on ties
      if (mo > bestv) { bestv = mo; besti = (unsigned)(base + tid + (p << 10)); }
    }
    float wm = dpp_max_f32(bestv);
    unsigned wmb = bcast63(__float_as_uint(wm));
    unsigned cand = (__float_as_uint(bestv) == wmb) ? (0xFFFFFFFFu - besti) : 0u;
    unsigned winv = bcast63(dpp_max_u32(cand));
    if (lane == 0) atomicMax(&s_key[it % 3u], ((unsigned long long)wmb << 32) | winv);
    if (tid == 0) s_key[(it + 1) % 3u] = 0ull;
    __syncthreads();
    if (tid == 0) {
      atomicMax(&gkey[it % 3u], s_key[it % 3u]);      // publish block winner
      __threadfence();
      atomicAdd(garr, 1ull);                          // arrive
      const unsigned long long tgt = (unsigned long long)FPS_SPLIT * it;
      while (__hip_atomic_load(garr, __ATOMIC_ACQUIRE, __HIP_MEMORY_SCOPE_AGENT) < tgt) {
        __builtin_amdgcn_s_sleep(1);
      }
      s_bkey = atomicMax(&gkey[it % 3u], 0ull);       // read-back (RMW)
      // reset slot for iteration it+2; ordered before its writers by the
      // spin of it+1 (they can't write until everyone passed arrive(it+1))
      __hip_atomic_store(&gkey[(it + 2) % 3u], 0ull,
                         __ATOMIC_RELAXED, __HIP_MEMORY_SCOPE_AGENT);
    }
    __syncthreads();
    unsigned long long k = s_bkey;
    int last = (int)(0xFFFFFFFFu - (unsigned)k);
    const float* q = px + (size_t)last * 3;   // broadcast L2 load
    qx = q[0]; qy = q[1]; qz = q[2];
    if (sub == 0 && tid == 0) {
      float* o = new_xyz + ((size_t)b * S + it) * 3;
      o[0] = qx; o[1] = qy; o[2] = qz;
    }
  }
}

// ---------------------------------------------------------------------------
// FPS, layers 1-3: T=N<=1024, one point per thread (regs) + coords mirrored
// in LDS for the winner lookup (no global reads in the loop).
__global__ void fps_small_kernel(const float* __restrict__ xyz,
    float* __restrict__ new_xyz, int N, int S) {
  const int b = blockIdx.x;
  const int tid = threadIdx.x;
  const int lane = tid & 63;
  const float* px = xyz + (size_t)b * N * 3;
  __shared__ float sx[1024], sy[1024], sz[1024];
  __shared__ unsigned long long s_key[3];
  float x = px[tid * 3 + 0], y = px[tid * 3 + 1], z = px[tid * 3 + 2];
  sx[tid] = x; sy[tid] = y; sz[tid] = z;
  if (tid < 3) s_key[tid] = 0ull;
  float mind = 1e10f;
  float qx = px[0], qy = px[1], qz = px[2];
  if (tid == 0) {
    float* o = new_xyz + (size_t)b * S * 3;
    o[0] = qx; o[1] = qy; o[2] = qz;
  }
  __syncthreads();
  for (unsigned it = 1; it < (unsigned)S; ++it) {
    float dx = __fsub_rn(x, qx);
    float dy = __fsub_rn(y, qy);
    float dz = __fsub_rn(z, qz);
    float d = __fadd_rn(__fadd_rn(__fmul_rn(dx, dx), __fmul_rn(dy, dy)), __fmul_rn(dz, dz));
    mind = fminf(mind, d);
    float wm = dpp_max_f32(mind);
    unsigned wmb = bcast63(__float_as_uint(wm));
    unsigned cand = (__float_as_uint(mind) == wmb) ? (0xFFFFFFFFu - (unsigned)tid) : 0u;
    unsigned winv = bcast63(dpp_max_u32(cand));
    if (lane == 0) atomicMax(&s_key[it % 3u], ((unsigned long long)wmb << 32) | winv);
    if (tid == 0) s_key[(it + 1) % 3u] = 0ull;
    __syncthreads();
    unsigned long long k = s_key[it % 3u];
    int last = (int)(0xFFFFFFFFu - (unsigned)k);
    qx = sx[last]; qy = sy[last]; qz = sz[last];   // LDS broadcast
    if (tid == 0) {
      float* o = new_xyz + ((size_t)b * S + it) * 3;
      o[0] = qx; o[1] = qy; o[2] = qz;
    }
  }
}

// ---------------------------------------------------------------------------
// Ball query: one wave per center; take the FIRST nsample indices (ascending)
// with d2 < r2 (== nsample smallest indices, matching top_k(-key)). Pad with
// the first hit (0 if no hits).
__global__ __launch_bounds__(256) void ballquery_kernel(const float* __restrict__ xyz,
    const float* __restrict__ centers, int* __restrict__ out_idx,
    int N, int S, int nsample, float r2) {
  int gw = (blockIdx.x * blockDim.x + threadIdx.x) >> 6;
  int lane = threadIdx.x & 63;
  int b = gw / S;
  int s = gw - b * S;
  const float* px = xyz + (size_t)b * N * 3;
  const float* cp = centers + ((size_t)b * S + s) * 3;
  float cx = cp[0], cy = cp[1], cz = cp[2];
  int* out = out_idx + ((size_t)b * S + s) * nsample;
  int cnt = 0;
  int firsti = 0;
  for (int base = 0; base < N; base += WAVE) {
    int i = base + lane;
    float dx = __fsub_rn(cx, px[i * 3 + 0]);
    float dy = __fsub_rn(cy, px[i * 3 + 1]);
    float dz = __fsub_rn(cz, px[i * 3 + 2]);
    float d = __fadd_rn(__fadd_rn(__fmul_rn(dx, dx), __fmul_rn(dy, dy)), __fmul_rn(dz, dz));
    bool hit = d < r2;
    unsigned long long m = __ballot(hit);
    if (hit) {
      int slot = cnt + __popcll(m & ((1ull << lane) - 1ull));
      if (slot < nsample) out[slot] = i;
    }
    if (cnt == 0 && m) firsti = base + __ffsll((unsigned long long)m) - 1;
    cnt += __popcll(m);
    if (cnt >= nsample) break;
  }
  for (int q = cnt + lane; q < nsample; q += WAVE) out[q] = firsti;
}

// ---------------------------------------------------------------------------
// Build X0 rows: [xyz[j]-center (3), feats[j] (ci)] for r=(b,s,k), c in [0,3+ci)
__global__ __launch_bounds__(256) void group_kernel(const float* __restrict__ xyz,
    const float* __restrict__ feats, const float* __restrict__ centers,
    const int* __restrict__ idx, float* __restrict__ X,
    int N, int S, int K, int ci, int R) {
  int t = blockIdx.x * blockDim.x + threadIdx.x;
  int C0 = ci + 3;
  int r = t / C0;
  if (r >= R) return;
  int c = t - r * C0;
  int g = r / K;          // b*S + s
  int b = g / S;
  int j = idx[r];
  float v;
  if (c < 3) v = __fsub_rn(xyz[((size_t)b * N + j) * 3 + c], centers[(size_t)g * 3 + c]);
  else       v = feats[((size_t)b * N + j) * ci + (c - 3)];
  X[(size_t)r * C0 + c] = v;
}

// ---------------------------------------------------------------------------
// Fused tiled f32 GEMM: Y(RxCo) = normReLU(A)(RxC) @ W(CxCo).
//  - if st_in != nullptr, A is normalized elementwise during LDS staging:
//      v = relu(gamma_in[c]*((a - mu[c])*rs[c]) + beta_in[c])
//    with mu/rs from st_in (prev sub-layer's sums; complete by stream order).
//  - per-channel sum/sumsq of Y accumulated into st_out (epilogue atomics)
//    -> replaces the separate stats pass (round-4 fusion).
// R % 64 == 0 always; C/Co guarded.
#define BM 64
#define BN 64
#define BK 16
__global__ __launch_bounds__(256) void mm_fused_kernel(const float* __restrict__ A,
    const float* __restrict__ W, float* __restrict__ Y,
    float* __restrict__ st_out, const float* __restrict__ st_in,
    const float* __restrict__ g_in, const float* __restrict__ b_in,
    int R, int C, int Co, float inv_n) {
  __shared__ float As[BK][BM + 4];
  __shared__ float Bs[BK][BN + 4];
  __shared__ float s_mu[260], s_rs[260], s_g[260], s_b[260];
  __shared__ float s_sum[BN], s_sq[BN];
  int r0 = blockIdx.x * BM;
  int n0 = blockIdx.y * BN;
  int tid = threadIdx.x;
  int tx = tid & 15, ty = tid >> 4;
  if (st_in) {
    for (int c = tid; c < C; c += 256) {
      float mu = st_in[c] * inv_n;
      float var = st_in[512 + c] * inv_n - mu * mu;
      s_mu[c] = mu; s_rs[c] = rsqrtf(var + 1e-5f);
      s_g[c] = g_in[c]; s_b[c] = b_in[c];
    }
  }
  if (tid < BN) { s_sum[tid] = 0.f; s_sq[tid] = 0.f; }
  __syncthreads();
  float acc[4][4] = {};
  for (int k0 = 0; k0 < C; k0 += BK) {
#pragma unroll
    for (int u = 0; u < 4; ++u) {
      int lin = tid + u * 256;
      int row = lin >> 4;
      int cc = lin & 15;
      int c = k0 + cc;
      float v = 0.f;
      if (c < C) {
        v = A[(size_t)(r0 + row) * C + c];
        if (st_in) {
          v = s_g[c] * ((v - s_mu[c]) * s_rs[c]) + s_b[c];
          v = v > 0.f ? v : 0.f;
        }
      }
      As[cc][row] = v;
    }
#pragma unroll
    for (int u = 0; u < 4; ++u) {
      int lin = tid + u * 256;
      int kk = lin >> 6;
      int n = lin & 63;
      int c = k0 + kk;
      Bs[kk][n] = (c < C && (n0 + n) < Co) ? W[(size_t)c * Co + n0 + n] : 0.f;
    }
    __syncthreads();
#pragma unroll
    for (int kk = 0; kk < BK; ++kk) {
      float a0[4], b0[4];
#pragma unroll
      for (int i = 0; i < 4; ++i) a0[i] = As[kk][ty * 4 + i];
#pragma unroll
      for (int jj = 0; jj < 4; ++jj) b0[jj] = Bs[kk][tx * 4 + jj];
#pragma unroll
      for (int i = 0; i < 4; ++i)
#pragma unroll
        for (int jj = 0; jj < 4; ++jj)
          acc[i][jj] = fmaf(a0[i], b0[jj], acc[i][jj]);
    }
    __syncthreads();
  }
#pragma unroll
  for (int i = 0; i < 4; ++i) {
    int r = r0 + ty * 4 + i;
#pragma unroll
    for (int jj = 0; jj < 4; ++jj) {
      int n = n0 + tx * 4 + jj;
      if (n < Co) Y[(size_t)r * Co + n] = acc[i][jj];
    }
  }
  // epilogue: per-column sum/sumsq of this block's tile -> LDS -> global
#pragma unroll
  for (int jj = 0; jj < 4; ++jj) {
    float cs = 0.f, cq = 0.f;
#pragma unroll
    for (int i = 0; i < 4; ++i) { float v = acc[i][jj]; cs += v; cq += v * v; }
    atomicAdd(&s_sum[tx * 4 + jj], cs);
    atomicAdd(&s_sq[tx * 4 + jj], cq);
  }
  __syncthreads();
  if (tid < BN) {
    int n = n0 + tid;
    if (n < Co) {
      atomicAdd(&st_out[n], s_sum[tid]);
      atomicAdd(&st_out[512 + n], s_sq[tid]);
    }
  }
}

// Last sub-layer: normalize+relu then max over the K samples of each group.
__global__ __launch_bounds__(256) void norm_relu_max_kernel(const float* __restrict__ Y,
    float* __restrict__ O, const float* __restrict__ st,
    const float* __restrict__ gamma, const float* __restrict__ beta,
    int G, int K, int Co, float inv_n) {
  int t = blockIdx.x * blockDim.x + threadIdx.x;
  if (t >= G * Co) return;
  int c = t & (Co - 1);
  int g = t / Co;
  float mu = st[c] * inv_n;
  float var = st[512 + c] * inv_n - mu * mu;
  float rs = rsqrtf(var + 1e-5f);
  float ga = gamma[c], be = beta[c];
  const float* yp = Y + (size_t)g * K * Co + c;
  float m = -1e30f;
  for (int k = 0; k < K; ++k) {
    float v = ga * ((yp[(size_t)k * Co] - mu) * rs) + be;
    m = fmaxf(m, v);
  }
  O[t] = m > 0.f ? m : 0.f;
}

// ---------------------------------------------------------------------------
extern "C" void kernel_launch(void* const* d_in, const int* in_sizes, int n_in,
                              void* d_out, int out_size, void* d_ws, size_t ws_size,
                              hipStream_t stream) {
  const float* pc = (const float*)d_in[0];
  float* out = (float*)d_out;
  char* wsb = (char*)d_ws;

  // ws layout: [0,1MB) ball idx; [1MB,+48KB) stats; [+48KB,+48.25KB) fps sync;
  // [3MB,37MB) bufA; [37MB,104MB) bufB
  int* ballidx = (int*)wsb;
  float* stats = (float*)(wsb + ((size_t)1 << 20));
  unsigned long long* fps_sync = (unsigned long long*)(stats + 12 * 1024);
  float* bufA = (float*)(wsb + ((size_t)3 << 20));
  float* bufB = (float*)(wsb + ((size_t)37 << 20));

  const int B = 8;
  static const int Ns[4] = {16384, 1024, 256, 64};
  static const int Ss[4] = {1024, 256, 64, 16};
  static const int Ks[4] = {32, 32, 16, 16};
  static const double Rr[4] = {0.02, 0.04, 0.06, 0.08};
  static const int Ci[4] = {3, 64, 128, 256};
  static const int mlp[4][4] = {{6,32,32,64},{67,64,64,128},{131,128,128,256},{259,256,256,512}};
  static const size_t ox[5] = {0, 393216, 417792, 423936, 425472};
  static const size_t of[5] = {425856, 819072, 1343360, 1605504, 1736576};

  split_kernel<<<(B * 16384 + 255) / 256, 256, 0, stream>>>(pc, out + ox[0], out + of[0], B * 16384);
  // zero stats (12K floats) + fps sync area (8 batches x 4 u64 = 64 floats);
  // ws is re-poisoned to 0xAA before every timed launch, so this must run
  // every call, before fps_big.
  zero_kernel<<<(12 * 1024 + 64 + 255) / 256, 256, 0, stream>>>(stats, 12 * 1024 + 64);

  for (int l = 0; l < 4; ++l) {
    const float* xyz = out + ox[l];
    const float* fts = out + of[l];
    float* nxyz = out + ox[l + 1];
    const int N = Ns[l], S = Ss[l], K = Ks[l], ci = Ci[l], C0 = ci + 3;
    const float r2 = (float)(Rr[l] * Rr[l]);

    if (l == 0) fps_big_kernel<<<B * FPS_SPLIT, 1024, 0, stream>>>(xyz, nxyz, fps_sync, N, S);
    else        fps_small_kernel<<<B, N, 0, stream>>>(xyz, nxyz, N, S);

    ballquery_kernel<<<(B * S) / 4, 256, 0, stream>>>(xyz, nxyz, ballidx, N, S, K, r2);

    const int R = B * S * K;
    {
      int total = R * C0;
      group_kernel<<<(total + 255) / 256, 256, 0, stream>>>(xyz, fts, nxyz, ballidx, bufA,
                                                            N, S, K, ci, R);
    }

    const float inv_n = 1.0f / (float)R;
    float* X = bufA; float* Y = bufB;
    const float* prev_st = nullptr;
    const float* prev_g = nullptr;
    const float* prev_b = nullptr;
    for (int j = 0; j < 3; ++j) {
      const int cin = mlp[l][j], cout = mlp[l][j + 1];
      const float* Wt = (const float*)d_in[1 + (l * 3 + j) * 3 + 0];
      const float* Ga = (const float*)d_in[1 + (l * 3 + j) * 3 + 1];
      const float* Be = (const float*)d_in[1 + (l * 3 + j) * 3 + 2];
      float* st = stats + (size_t)(l * 3 + j) * 1024;
      dim3 grid(R / 64, (cout + 63) / 64);
      mm_fused_kernel<<<grid, 256, 0, stream>>>(X, Wt, Y, st, prev_st, prev_g, prev_b,
                                                R, cin, cout, inv_n);
      if (j < 2) {
        prev_st = st; prev_g = Ga; prev_b = Be;
        float* tswap = X; X = Y; Y = tswap;
      } else {
        int G = B * S;
        int tot = G * cout;
        norm_relu_max_kernel<<<(tot + 255) / 256, 256, 0, stream>>>(Y, out + of[l + 1], st, Ga, Be,
                                                                    G, K, cout, inv_n);
      }
    }
  }
}

// Round 9
// 2857.937 us; speedup vs baseline: 1.6400x; 1.6400x over previous
//
#include <hip/hip_runtime.h>

#define WAVE 64

// ---------------------------------------------------------------------------
// split pointcloud (B,N,6) -> xyz (B,N,3) + feats (B,N,3); also zeros the
// stats area (merged to save a dispatch — round-9: launch gaps ~10-20us each).
__global__ __launch_bounds__(256) void split_zero_kernel(const float* __restrict__ pc,
    float* __restrict__ xyz, float* __restrict__ feats, int total,
    float* __restrict__ stats, int n_stats) {
  int t = blockIdx.x * blockDim.x + threadIdx.x;
  if (t < n_stats) stats[t] = 0.f;
  if (t >= total) return;
  const float* p = pc + (size_t)t * 6;
  xyz[t * 3 + 0] = p[0]; xyz[t * 3 + 1] = p[1]; xyz[t * 3 + 2] = p[2];
  feats[t * 3 + 0] = p[3]; feats[t * 3 + 1] = p[4]; feats[t * 3 + 2] = p[5];
}

// ---------------------------------------------------------------------------
// Wave-wide reductions via DPP (VALU pipe only — no ds_swizzle LDS traffic).
// rocPRIM pattern: row_shr 1/2/4/8 + row_bcast15/31; full max lands in lane 63.
__device__ __forceinline__ float dpp_max_f32(float v) {
#define DPP_STEP_F(ctrl) { int t_ = __builtin_amdgcn_update_dpp( \
      __float_as_int(v), __float_as_int(v), ctrl, 0xf, 0xf, false); \
    v = fmaxf(v, __int_as_float(t_)); }
  DPP_STEP_F(0x111) DPP_STEP_F(0x112) DPP_STEP_F(0x114)
  DPP_STEP_F(0x118) DPP_STEP_F(0x142) DPP_STEP_F(0x143)
#undef DPP_STEP_F
  return v;  // valid in lane 63
}
__device__ __forceinline__ unsigned dpp_max_u32(unsigned v) {
#define DPP_STEP_U(ctrl) { unsigned t_ = (unsigned)__builtin_amdgcn_update_dpp( \
      (int)v, (int)v, ctrl, 0xf, 0xf, false); \
    v = (t_ > v) ? t_ : v; }
  DPP_STEP_U(0x111) DPP_STEP_U(0x112) DPP_STEP_U(0x114)
  DPP_STEP_U(0x118) DPP_STEP_U(0x142) DPP_STEP_U(0x143)
#undef DPP_STEP_U
  return v;  // valid in lane 63
}
__device__ __forceinline__ unsigned bcast63(unsigned v) {
  return (unsigned)__builtin_amdgcn_readlane((int)v, 63);
}

// ---------------------------------------------------------------------------
// FPS, layer 0: N=16384, single block/batch — ROUND-4 STRUCTURE REVERTED.
// Round-8 post-mortem: 4-block split + per-iter device-scope sync cost ~3us/
// iter (3-5 serialized LLC round-trips across XCDs) > the 1.25us of compute
// it saved => 3630us. Single-block at 1693us is this kernel's measured floor
// (regs+AGPR, pk-packed, LDS variants all ~1700; per-CU VALUBusy ~90%).
// Exact semantics: ((dx*dx+dy*dy)+dz*dz) with explicit _rn ops (no FMA);
// tie-break = smallest index via inverted-idx u32 max.
__global__ __launch_bounds__(1024, 4) void fps_big_kernel(const float* __restrict__ xyz,
    float* __restrict__ new_xyz, int N, int S) {
  const int b = blockIdx.x;
  const int tid = threadIdx.x;
  const int lane = tid & 63;
  const float* px = xyz + (size_t)b * N * 3;
  __shared__ unsigned long long s_key[3];
  float rx[16], ry[16], rz[16], mind[16];
#pragma unroll
  for (int p = 0; p < 16; ++p) {
    int i = tid + p * 1024;
    rx[p] = px[i * 3 + 0]; ry[p] = px[i * 3 + 1]; rz[p] = px[i * 3 + 2];
    asm volatile("" : "+v"(rx[p]), "+v"(ry[p]), "+v"(rz[p]));
    mind[p] = 1e10f;
  }
  if (tid < 3) s_key[tid] = 0ull;
  float qx = px[0], qy = px[1], qz = px[2];   // pick 0 is always index 0
  if (tid == 0) {
    float* o = new_xyz + (size_t)b * S * 3;
    o[0] = qx; o[1] = qy; o[2] = qz;
  }
  __syncthreads();
  for (unsigned it = 1; it < (unsigned)S; ++it) {
    float bestv = -1.f; unsigned besti = 0;
#pragma unroll
    for (int p = 0; p < 16; ++p) {
      float dx = __fsub_rn(rx[p], qx);
      float dy = __fsub_rn(ry[p], qy);
      float dz = __fsub_rn(rz[p], qz);
      float d = __fadd_rn(__fadd_rn(__fmul_rn(dx, dx), __fmul_rn(dy, dy)), __fmul_rn(dz, dz));
      float mo = fminf(mind[p], d);
      mind[p] = mo;
      // p ascending => index ascending within thread: keeps first max on ties
      if (mo > bestv) { bestv = mo; besti = (unsigned)(tid + p * 1024); }
    }
    float wm = dpp_max_f32(bestv);
    unsigned wmb = bcast63(__float_as_uint(wm));
    unsigned cand = (__float_as_uint(bestv) == wmb) ? (0xFFFFFFFFu - besti) : 0u;
    unsigned winv = bcast63(dpp_max_u32(cand));
    if (lane == 0) atomicMax(&s_key[it % 3u], ((unsigned long long)wmb << 32) | winv);
    if (tid == 0) s_key[(it + 1) % 3u] = 0ull;
    __syncthreads();
    unsigned long long k = s_key[it % 3u];
    int last = (int)(0xFFFFFFFFu - (unsigned)k);
    const float* q = px + (size_t)last * 3;  // broadcast L2 load
    qx = q[0]; qy = q[1]; qz = q[2];
    if (tid == 0) {
      float* o = new_xyz + ((size_t)b * S + it) * 3;
      o[0] = qx; o[1] = qy; o[2] = qz;
    }
  }
}

// ---------------------------------------------------------------------------
// FPS, layers 1-3: T=N<=1024, one point per thread (regs) + coords mirrored
// in LDS for the winner lookup (no global reads in the loop).
__global__ void fps_small_kernel(const float* __restrict__ xyz,
    float* __restrict__ new_xyz, int N, int S) {
  const int b = blockIdx.x;
  const int tid = threadIdx.x;
  const int lane = tid & 63;
  const float* px = xyz + (size_t)b * N * 3;
  __shared__ float sx[1024], sy[1024], sz[1024];
  __shared__ unsigned long long s_key[3];
  float x = px[tid * 3 + 0], y = px[tid * 3 + 1], z = px[tid * 3 + 2];
  sx[tid] = x; sy[tid] = y; sz[tid] = z;
  if (tid < 3) s_key[tid] = 0ull;
  float mind = 1e10f;
  float qx = px[0], qy = px[1], qz = px[2];
  if (tid == 0) {
    float* o = new_xyz + (size_t)b * S * 3;
    o[0] = qx; o[1] = qy; o[2] = qz;
  }
  __syncthreads();
  for (unsigned it = 1; it < (unsigned)S; ++it) {
    float dx = __fsub_rn(x, qx);
    float dy = __fsub_rn(y, qy);
    float dz = __fsub_rn(z, qz);
    float d = __fadd_rn(__fadd_rn(__fmul_rn(dx, dx), __fmul_rn(dy, dy)), __fmul_rn(dz, dz));
    mind = fminf(mind, d);
    float wm = dpp_max_f32(mind);
    unsigned wmb = bcast63(__float_as_uint(wm));
    unsigned cand = (__float_as_uint(mind) == wmb) ? (0xFFFFFFFFu - (unsigned)tid) : 0u;
    unsigned winv = bcast63(dpp_max_u32(cand));
    if (lane == 0) atomicMax(&s_key[it % 3u], ((unsigned long long)wmb << 32) | winv);
    if (tid == 0) s_key[(it + 1) % 3u] = 0ull;
    __syncthreads();
    unsigned long long k = s_key[it % 3u];
    int last = (int)(0xFFFFFFFFu - (unsigned)k);
    qx = sx[last]; qy = sy[last]; qz = sz[last];   // LDS broadcast
    if (tid == 0) {
      float* o = new_xyz + ((size_t)b * S + it) * 3;
      o[0] = qx; o[1] = qy; o[2] = qz;
    }
  }
}

// ---------------------------------------------------------------------------
// Fused ball query + grouping (round 9: kills the separate group dispatch and
// the ballidx round-trip). One wave per center: find the FIRST nsample
// indices (ascending) with d2 < r2 (== top_k(-key) semantics), pad with the
// first hit (0 if none), stash them in LDS, then gather-write the X rows
// [xyz[j]-center (3), feats[j] (ci)] for the center's K samples directly.
__global__ __launch_bounds__(256) void ballgroup_kernel(const float* __restrict__ xyz,
    const float* __restrict__ feats, const float* __restrict__ centers,
    float* __restrict__ X, int N, int S, int K, int ci, float r2) {
  __shared__ int s_sel[4][32];            // K <= 32
  const int wid = threadIdx.x >> 6;
  const int lane = threadIdx.x & 63;
  const int gw = blockIdx.x * 4 + wid;    // b*S + s
  const int b = gw / S;
  const float* px = xyz + (size_t)b * N * 3;
  const float* cp = centers + (size_t)gw * 3;
  float cx = cp[0], cy = cp[1], cz = cp[2];
  int cnt = 0;
  int firsti = 0;
  for (int base = 0; base < N; base += WAVE) {
    int i = base + lane;
    float dx = __fsub_rn(cx, px[i * 3 + 0]);
    float dy = __fsub_rn(cy, px[i * 3 + 1]);
    float dz = __fsub_rn(cz, px[i * 3 + 2]);
    float d = __fadd_rn(__fadd_rn(__fmul_rn(dx, dx), __fmul_rn(dy, dy)), __fmul_rn(dz, dz));
    bool hit = d < r2;
    unsigned long long m = __ballot(hit);
    if (hit) {
      int slot = cnt + __popcll(m & ((1ull << lane) - 1ull));
      if (slot < K) s_sel[wid][slot] = i;
    }
    if (cnt == 0 && m) firsti = base + __ffsll((unsigned long long)m) - 1;
    cnt += __popcll(m);
    if (cnt >= K) break;
  }
  for (int q = cnt + lane; q < K; q += WAVE) s_sel[wid][q] = firsti;
  __syncthreads();   // make each wave's sel visible to its own later reads
  const int C0 = ci + 3;
  const float* pf = feats + (size_t)b * N * ci;
  float* Xg = X + (size_t)gw * K * C0;
  for (int k = 0; k < K; ++k) {
    int j = s_sel[wid][k];
    const float* fj = pf + (size_t)j * ci;
    float* xr = Xg + (size_t)k * C0;
    float jx = px[j * 3 + 0], jy = px[j * 3 + 1], jz = px[j * 3 + 2];
    for (int c = lane; c < C0; c += WAVE) {
      float v;
      if (c == 0)      v = __fsub_rn(jx, cx);
      else if (c == 1) v = __fsub_rn(jy, cy);
      else if (c == 2) v = __fsub_rn(jz, cz);
      else             v = fj[c - 3];
      xr[c] = v;
    }
  }
}

// ---------------------------------------------------------------------------
// Fused tiled f32 GEMM: Y(RxCo) = normReLU(A)(RxC) @ W(CxCo).
//  - if st_in != nullptr, A is normalized elementwise during LDS staging:
//      v = relu(gamma_in[c]*((a - mu[c])*rs[c]) + beta_in[c])
//    with mu/rs from st_in (prev sub-layer's sums; complete by stream order).
//  - per-channel sum/sumsq of Y accumulated into st_out (epilogue atomics)
//    -> replaces the separate stats pass (round-4 fusion).
// R % 64 == 0 always; C/Co guarded.
#define BM 64
#define BN 64
#define BK 16
__global__ __launch_bounds__(256) void mm_fused_kernel(const float* __restrict__ A,
    const float* __restrict__ W, float* __restrict__ Y,
    float* __restrict__ st_out, const float* __restrict__ st_in,
    const float* __restrict__ g_in, const float* __restrict__ b_in,
    int R, int C, int Co, float inv_n) {
  __shared__ float As[BK][BM + 4];
  __shared__ float Bs[BK][BN + 4];
  __shared__ float s_mu[260], s_rs[260], s_g[260], s_b[260];
  __shared__ float s_sum[BN], s_sq[BN];
  int r0 = blockIdx.x * BM;
  int n0 = blockIdx.y * BN;
  int tid = threadIdx.x;
  int tx = tid & 15, ty = tid >> 4;
  if (st_in) {
    for (int c = tid; c < C; c += 256) {
      float mu = st_in[c] * inv_n;
      float var = st_in[512 + c] * inv_n - mu * mu;
      s_mu[c] = mu; s_rs[c] = rsqrtf(var + 1e-5f);
      s_g[c] = g_in[c]; s_b[c] = b_in[c];
    }
  }
  if (tid < BN) { s_sum[tid] = 0.f; s_sq[tid] = 0.f; }
  __syncthreads();
  float acc[4][4] = {};
  for (int k0 = 0; k0 < C; k0 += BK) {
#pragma unroll
    for (int u = 0; u < 4; ++u) {
      int lin = tid + u * 256;
      int row = lin >> 4;
      int cc = lin & 15;
      int c = k0 + cc;
      float v = 0.f;
      if (c < C) {
        v = A[(size_t)(r0 + row) * C + c];
        if (st_in) {
          v = s_g[c] * ((v - s_mu[c]) * s_rs[c]) + s_b[c];
          v = v > 0.f ? v : 0.f;
        }
      }
      As[cc][row] = v;
    }
#pragma unroll
    for (int u = 0; u < 4; ++u) {
      int lin = tid + u * 256;
      int kk = lin >> 6;
      int n = lin & 63;
      int c = k0 + kk;
      Bs[kk][n] = (c < C && (n0 + n) < Co) ? W[(size_t)c * Co + n0 + n] : 0.f;
    }
    __syncthreads();
#pragma unroll
    for (int kk = 0; kk < BK; ++kk) {
      float a0[4], b0[4];
#pragma unroll
      for (int i = 0; i < 4; ++i) a0[i] = As[kk][ty * 4 + i];
#pragma unroll
      for (int jj = 0; jj < 4; ++jj) b0[jj] = Bs[kk][tx * 4 + jj];
#pragma unroll
      for (int i = 0; i < 4; ++i)
#pragma unroll
        for (int jj = 0; jj < 4; ++jj)
          acc[i][jj] = fmaf(a0[i], b0[jj], acc[i][jj]);
    }
    __syncthreads();
  }
#pragma unroll
  for (int i = 0; i < 4; ++i) {
    int r = r0 + ty * 4 + i;
#pragma unroll
    for (int jj = 0; jj < 4; ++jj) {
      int n = n0 + tx * 4 + jj;
      if (n < Co) Y[(size_t)r * Co + n] = acc[i][jj];
    }
  }
  // epilogue: per-column sum/sumsq of this block's tile -> LDS -> global
#pragma unroll
  for (int jj = 0; jj < 4; ++jj) {
    float cs = 0.f, cq = 0.f;
#pragma unroll
    for (int i = 0; i < 4; ++i) { float v = acc[i][jj]; cs += v; cq += v * v; }
    atomicAdd(&s_sum[tx * 4 + jj], cs);
    atomicAdd(&s_sq[tx * 4 + jj], cq);
  }
  __syncthreads();
  if (tid < BN) {
    int n = n0 + tid;
    if (n < Co) {
      atomicAdd(&st_out[n], s_sum[tid]);
      atomicAdd(&st_out[512 + n], s_sq[tid]);
    }
  }
}

// Last sub-layer: normalize+relu then max over the K samples of each group.
__global__ __launch_bounds__(256) void norm_relu_max_kernel(const float* __restrict__ Y,
    float* __restrict__ O, const float* __restrict__ st,
    const float* __restrict__ gamma, const float* __restrict__ beta,
    int G, int K, int Co, float inv_n) {
  int t = blockIdx.x * blockDim.x + threadIdx.x;
  if (t >= G * Co) return;
  int c = t & (Co - 1);
  int g = t / Co;
  float mu = st[c] * inv_n;
  float var = st[512 + c] * inv_n - mu * mu;
  float rs = rsqrtf(var + 1e-5f);
  float ga = gamma[c], be = beta[c];
  const float* yp = Y + (size_t)g * K * Co + c;
  float m = -1e30f;
  for (int k = 0; k < K; ++k) {
    float v = ga * ((yp[(size_t)k * Co] - mu) * rs) + be;
    m = fmaxf(m, v);
  }
  O[t] = m > 0.f ? m : 0.f;
}

// ---------------------------------------------------------------------------
extern "C" void kernel_launch(void* const* d_in, const int* in_sizes, int n_in,
                              void* d_out, int out_size, void* d_ws, size_t ws_size,
                              hipStream_t stream) {
  const float* pc = (const float*)d_in[0];
  float* out = (float*)d_out;
  char* wsb = (char*)d_ws;

  // ws layout: [1MB,+48KB) stats; [3MB,37MB) bufA; [37MB,104MB) bufB
  float* stats = (float*)(wsb + ((size_t)1 << 20));
  float* bufA = (float*)(wsb + ((size_t)3 << 20));
  float* bufB = (float*)(wsb + ((size_t)37 << 20));

  const int B = 8;
  static const int Ns[4] = {16384, 1024, 256, 64};
  static const int Ss[4] = {1024, 256, 64, 16};
  static const int Ks[4] = {32, 32, 16, 16};
  static const double Rr[4] = {0.02, 0.04, 0.06, 0.08};
  static const int Ci[4] = {3, 64, 128, 256};
  static const int mlp[4][4] = {{6,32,32,64},{67,64,64,128},{131,128,128,256},{259,256,256,512}};
  static const size_t ox[5] = {0, 393216, 417792, 423936, 425472};
  static const size_t of[5] = {425856, 819072, 1343360, 1605504, 1736576};

  // split + stats-zero merged (ws is re-poisoned to 0xAA before every timed
  // launch, so the zero must run every call, before the first mm).
  split_zero_kernel<<<(B * 16384 + 255) / 256, 256, 0, stream>>>(
      pc, out + ox[0], out + of[0], B * 16384, stats, 12 * 1024);

  for (int l = 0; l < 4; ++l) {
    const float* xyz = out + ox[l];
    const float* fts = out + of[l];
    float* nxyz = out + ox[l + 1];
    const int N = Ns[l], S = Ss[l], K = Ks[l], ci = Ci[l], C0 = ci + 3;
    const float r2 = (float)(Rr[l] * Rr[l]);

    if (l == 0) fps_big_kernel<<<B, 1024, 0, stream>>>(xyz, nxyz, N, S);
    else        fps_small_kernel<<<B, N, 0, stream>>>(xyz, nxyz, N, S);

    ballgroup_kernel<<<(B * S) / 4, 256, 0, stream>>>(xyz, fts, nxyz, bufA,
                                                      N, S, K, ci, r2);

    const int R = B * S * K;
    const float inv_n = 1.0f / (float)R;
    float* X = bufA; float* Y = bufB;
    const float* prev_st = nullptr;
    const float* prev_g = nullptr;
    const float* prev_b = nullptr;
    for (int j = 0; j < 3; ++j) {
      const int cin = mlp[l][j], cout = mlp[l][j + 1];
      const float* Wt = (const float*)d_in[1 + (l * 3 + j) * 3 + 0];
      const float* Ga = (const float*)d_in[1 + (l * 3 + j) * 3 + 1];
      const float* Be = (const float*)d_in[1 + (l * 3 + j) * 3 + 2];
      float* st = stats + (size_t)(l * 3 + j) * 1024;
      dim3 grid(R / 64, (cout + 63) / 64);
      mm_fused_kernel<<<grid, 256, 0, stream>>>(X, Wt, Y, st, prev_st, prev_g, prev_b,
                                                R, cin, cout, inv_n);
      if (j < 2) {
        prev_st = st; prev_g = Ga; prev_b = Be;
        float* tswap = X; X = Y; Y = tswap;
      } else {
        int G = B * S;
        int tot = G * cout;
        norm_relu_max_kernel<<<(tot + 255) / 256, 256, 0, stream>>>(Y, out + of[l + 1], st, Ga, Be,
                                                                    G, K, cout, inv_n);
      }
    }
  }
}